// Round 19
// baseline (870.951 us; speedup 1.0000x reference)
//
#include <hip/hip_runtime.h>
#include <hip/hip_fp16.h>

#define NS 0.2f  // leaky_relu negative slope

// NOTE (R11/R14/R15/R16 lessons): k_gat_fused_h throughput is a pure function
// of occupancy: 64 VGPR -> 38% occ; every register spent on ILP lost more TLP
// than it gained (reg-hoist, NE=8, index prefetch, s_setprio all regressed).
// Wins: zero-register structural changes only (R18 int2 epack; R19 fp16 ea).

// ===================== CSR construction =====================
__global__ void k_deg(const int* __restrict__ dst, int* degi, int E){
  int stride = gridDim.x * blockDim.x;
  for(int e = blockIdx.x * blockDim.x + threadIdx.x; e < E; e += stride)
    atomicAdd(&degi[dst[e]], 1);
}

__device__ __forceinline__ int wave_iscan(int v, int lane){
  #pragma unroll
  for(int o = 1; o < 64; o <<= 1){
    int t = __shfl_up(v, o);
    if(lane >= o) v += t;
  }
  return v;
}

// ---- 3-phase multi-block exclusive scan ----
__global__ __launch_bounds__(1024) void k_scan_sum(
    const int* __restrict__ deg, int* __restrict__ bsum, int n)
{
  __shared__ int wsum[16];
  const int lane = threadIdx.x & 63;
  const int w = threadIdx.x >> 6;
  int idx = blockIdx.x * 1024 + threadIdx.x;
  int v = (idx < n) ? deg[idx] : 0;
  #pragma unroll
  for(int o = 32; o; o >>= 1) v += __shfl_xor(v, o);
  if(lane == 0) wsum[w] = v;
  __syncthreads();
  if(w == 0){
    int s = (lane < 16) ? wsum[lane] : 0;
    #pragma unroll
    for(int o = 8; o; o >>= 1) s += __shfl_xor(s, o);
    if(lane == 0) bsum[blockIdx.x] = s;
  }
}

__global__ __launch_bounds__(128) void k_scan_bsum(
    int* __restrict__ bsum, int* __restrict__ rowoff, int B, int n)
{
  __shared__ int wtot[2];
  const int lane = threadIdx.x & 63;
  const int w = threadIdx.x >> 6;
  int t = threadIdx.x;
  int v = (t < B) ? bsum[t] : 0;
  int inc = wave_iscan(v, lane);
  if(lane == 63) wtot[w] = inc;
  __syncthreads();
  int off = (w > 0) ? wtot[0] : 0;
  if(t < B) bsum[t] = off + inc - v;   // exclusive
  if(t == 0) rowoff[n] = wtot[0] + wtot[1];
}

__global__ __launch_bounds__(1024) void k_scan_apply(
    const int* __restrict__ deg, const int* __restrict__ bsum,
    int* __restrict__ rowoff, int* __restrict__ pos, int n)
{
  __shared__ int wsum[16];
  const int lane = threadIdx.x & 63;
  const int w = threadIdx.x >> 6;
  int idx = blockIdx.x * 1024 + threadIdx.x;
  int v = (idx < n) ? deg[idx] : 0;
  int inc = wave_iscan(v, lane);
  if(lane == 63) wsum[w] = inc;
  __syncthreads();
  if(w == 0){
    int s = (lane < 16) ? wsum[lane] : 0;
    s = wave_iscan(s, lane);
    if(lane < 16) wsum[lane] = s;
  }
  __syncthreads();
  int woff = (w > 0) ? wsum[w - 1] : 0;
  if(idx < n){
    int ex = bsum[blockIdx.x] + woff + inc - v;
    rowoff[idx] = ex;
    pos[idx] = ex;
  }
}

// writes packed {e, src[e]} at CSR slot (R18: removes eidx->src dependent hop)
__global__ void k_fill(const int* __restrict__ dst, const int* __restrict__ src,
                       int* pos, int2* epack, int E){
  int stride = gridDim.x * blockDim.x;
  for(int e = blockIdx.x * blockDim.x + threadIdx.x; e < E; e += stride){
    int slot = atomicAdd(&pos[dst[e]], 1);
    epack[slot] = make_int2(e, src[e]);
  }
}

// fp32 ea -> fp16 (data path): halves the gathered row bytes in k_gat_fused_h
__global__ __launch_bounds__(256) void k_cvt_ea_h(
    const float* __restrict__ ea, __half* __restrict__ eah, long total2)
{
  long stride = (long)gridDim.x * blockDim.x;
  const float2* in = (const float2*)ea;
  __half2* out = (__half2*)eah;
  for(long i = (long)blockIdx.x * blockDim.x + threadIdx.x; i < total2; i += stride){
    float2 v = in[i];
    out[i] = __floats2half2_rn(v.x, v.y);
  }
}

// ===================== tiled GEMM: C = A @ W^T + b (k-major LDS, float4 reads) =====================
#define BM 64
#define BN 64
#define BK 16
__global__ __launch_bounds__(256) void k_gemm(
    const float* __restrict__ A, const float* __restrict__ W,
    const float* __restrict__ b, float* __restrict__ C,
    int n, int K, int M, int dorelu)
{
  __shared__ float As[BK][BM + 4];
  __shared__ float Bs[BK][BN + 4];
  const int bi = blockIdx.x * BM;
  const int bj = blockIdx.y * BN;
  const int tid = threadIdx.x;
  const int tr = tid / 16, tc = tid % 16;
  float acc[4][4] = {};
  for(int k0 = 0; k0 < K; k0 += BK){
    for(int l = tid; l < BM * BK; l += 256){
      int c = l % BK, r = l / BK;
      int gr = bi + r, gc = k0 + c;
      As[c][r] = (gr < n && gc < K) ? A[(long)gr * K + gc] : 0.0f;
    }
    for(int l = tid; l < BN * BK; l += 256){
      int c = l % BK, r = l / BK;
      int gr = bj + r, gc = k0 + c;
      Bs[c][r] = (gr < M && gc < K) ? W[(long)gr * K + gc] : 0.0f;
    }
    __syncthreads();
    #pragma unroll
    for(int kk = 0; kk < BK; ++kk){
      float4 av = *(const float4*)&As[kk][tr * 4];
      float4 bv = *(const float4*)&Bs[kk][tc * 4];
      acc[0][0] = fmaf(av.x, bv.x, acc[0][0]); acc[0][1] = fmaf(av.x, bv.y, acc[0][1]);
      acc[0][2] = fmaf(av.x, bv.z, acc[0][2]); acc[0][3] = fmaf(av.x, bv.w, acc[0][3]);
      acc[1][0] = fmaf(av.y, bv.x, acc[1][0]); acc[1][1] = fmaf(av.y, bv.y, acc[1][1]);
      acc[1][2] = fmaf(av.y, bv.z, acc[1][2]); acc[1][3] = fmaf(av.y, bv.w, acc[1][3]);
      acc[2][0] = fmaf(av.z, bv.x, acc[2][0]); acc[2][1] = fmaf(av.z, bv.y, acc[2][1]);
      acc[2][2] = fmaf(av.z, bv.z, acc[2][2]); acc[2][3] = fmaf(av.z, bv.w, acc[2][3]);
      acc[3][0] = fmaf(av.w, bv.x, acc[3][0]); acc[3][1] = fmaf(av.w, bv.y, acc[3][1]);
      acc[3][2] = fmaf(av.w, bv.z, acc[3][2]); acc[3][3] = fmaf(av.w, bv.w, acc[3][3]);
    }
    __syncthreads();
  }
  for(int r = 0; r < 4; r++){
    int gr = bi + tr * 4 + r;
    if(gr >= n) continue;
    for(int c = 0; c < 4; c++){
      int gc = bj + tc * 4 + c;
      if(gc >= M) continue;
      float val = acc[r][c] + b[gc];
      C[(long)gr * M + gc] = dorelu ? fmaxf(val, 0.0f) : val;
    }
  }
}

// fp16-output variant (data-path xl/xr tables)
__global__ __launch_bounds__(256) void k_gemm_h(
    const float* __restrict__ A, const float* __restrict__ W,
    const float* __restrict__ b, __half* __restrict__ C,
    int n, int K, int M)
{
  __shared__ float As[BK][BM + 4];
  __shared__ float Bs[BK][BN + 4];
  const int bi = blockIdx.x * BM;
  const int bj = blockIdx.y * BN;
  const int tid = threadIdx.x;
  const int tr = tid / 16, tc = tid % 16;
  float acc[4][4] = {};
  for(int k0 = 0; k0 < K; k0 += BK){
    for(int l = tid; l < BM * BK; l += 256){
      int c = l % BK, r = l / BK;
      int gr = bi + r, gc = k0 + c;
      As[c][r] = (gr < n && gc < K) ? A[(long)gr * K + gc] : 0.0f;
    }
    for(int l = tid; l < BN * BK; l += 256){
      int c = l % BK, r = l / BK;
      int gr = bj + r, gc = k0 + c;
      Bs[c][r] = (gr < M && gc < K) ? W[(long)gr * K + gc] : 0.0f;
    }
    __syncthreads();
    #pragma unroll
    for(int kk = 0; kk < BK; ++kk){
      float4 av = *(const float4*)&As[kk][tr * 4];
      float4 bv = *(const float4*)&Bs[kk][tc * 4];
      acc[0][0] = fmaf(av.x, bv.x, acc[0][0]); acc[0][1] = fmaf(av.x, bv.y, acc[0][1]);
      acc[0][2] = fmaf(av.x, bv.z, acc[0][2]); acc[0][3] = fmaf(av.x, bv.w, acc[0][3]);
      acc[1][0] = fmaf(av.y, bv.x, acc[1][0]); acc[1][1] = fmaf(av.y, bv.y, acc[1][1]);
      acc[1][2] = fmaf(av.y, bv.z, acc[1][2]); acc[1][3] = fmaf(av.y, bv.w, acc[1][3]);
      acc[2][0] = fmaf(av.z, bv.x, acc[2][0]); acc[2][1] = fmaf(av.z, bv.y, acc[2][1]);
      acc[2][2] = fmaf(av.z, bv.z, acc[2][2]); acc[2][3] = fmaf(av.z, bv.w, acc[2][3]);
      acc[3][0] = fmaf(av.w, bv.x, acc[3][0]); acc[3][1] = fmaf(av.w, bv.y, acc[3][1]);
      acc[3][2] = fmaf(av.w, bv.z, acc[3][2]); acc[3][3] = fmaf(av.w, bv.w, acc[3][3]);
    }
    __syncthreads();
  }
  for(int r = 0; r < 4; r++){
    int gr = bi + tr * 4 + r;
    if(gr >= n) continue;
    int gc0 = bj + tc * 4;
    float v[4];
    #pragma unroll
    for(int c = 0; c < 4; c++){
      int gc = gc0 + c;
      v[c] = (gc < M) ? acc[r][c] + b[gc] : 0.0f;
    }
    __half* Crow = C + (long)gr * M;
    if(gc0 + 3 < M){
      *(__half2*)(Crow + gc0)     = __halves2half2(__float2half(v[0]), __float2half(v[1]));
      *(__half2*)(Crow + gc0 + 2) = __halves2half2(__float2half(v[2]), __float2half(v[3]));
    } else {
      for(int c = 0; c < 4; c++){
        int gc = gc0 + c;
        if(gc < M) Crow[gc] = __float2half(v[c]);
      }
    }
  }
}

static void gemm_launch(const float* A, const float* W, const float* b, float* C,
                        int n, int K, int M, int relu, hipStream_t s){
  dim3 grid((n + BM - 1) / BM, (M + BN - 1) / BN);
  k_gemm<<<grid, 256, 0, s>>>(A, W, b, C, n, K, M, relu);
}

static void gemm_h_launch(const float* A, const float* W, const float* b, __half* C,
                          int n, int K, int M, hipStream_t s){
  dim3 grid((n + BM - 1) / BM, (M + BN - 1) / BN);
  k_gemm_h<<<grid, 256, 0, s>>>(A, W, b, C, n, K, M);
}

__device__ __forceinline__ float lkrelu(float t){ return (t > 0.0f) ? t : NS * t; }

// ===================== fused GATv2 (fp32, rule path): NE=4 =====================
template<int G, int F>
__global__ __launch_bounds__(256) void k_gat_fused(
    const float* __restrict__ xl, const float* __restrict__ xr,
    const float* __restrict__ ea,
    const int* __restrict__ rowoff, const int2* __restrict__ epack,
    const float* __restrict__ We, const float* __restrict__ att,
    const float* __restrict__ bias, float* __restrict__ out,
    int n, int dorelu)
{
  constexpr int NG = 256 / G;
  constexpr int FQ = F / 4;
  __shared__ float4 sWeT[18 * FQ];
  __shared__ float4 sAtt[FQ];
  __shared__ float4 sEa[NG][18];
  __shared__ float  sEamAcc[NG][18];
  __shared__ int    sIdx[NG][2][4];

  const int tid = threadIdx.x;
  for(int idx = tid; idx < F * 18; idx += 256){
    int f = idx / 18, k = idx % 18;
    ((float*)sWeT)[k * F + f] = We[idx];
  }
  for(int f = tid; f < F; f += 256) ((float*)sAtt)[f] = att[f];
  __syncthreads();

  const int g = tid / G, gl = tid % G;
  const bool act = (gl * 4 < F);
  const int glc = act ? gl : 0;
  const float4 av = sAtt[glc];

  for(int node = blockIdx.x * NG + g; node < n; node += gridDim.x * NG){
    const int r0 = rowoff[node], r1 = rowoff[node + 1];
    const int deg = r1 - r0;
    if(gl < 18) sEamAcc[g][gl] = 0.0f;
    float4 xlv = *(const float4*)(xl + (long)node * F + glc * 4);
    float4 xrv = *(const float4*)(xr + (long)node * F + glc * 4);
    float m = -3.4e38f, denom = 0.0f;
    float4 acc = make_float4(0.f, 0.f, 0.f, 0.f);

    for(int p = r0; p < r1; p += 4){
      if(gl < 4){
        int pp = p + gl; int e = -1, s = 0;
        if(pp < r1){ int2 es = epack[pp]; e = es.x; s = es.y; }
        sIdx[g][0][gl] = e; sIdx[g][1][gl] = s;
      }
      #pragma unroll
      for(int t = 0; t < (36 + G - 1) / G; ++t){
        int u = t * G + gl;
        if(u < 36){
          int ne = u & 3, k2 = u >> 2;
          int e = sIdx[g][0][ne];
          float2 v = (e >= 0) ? *(const float2*)(ea + (long)e * 18 + k2 * 2)
                              : make_float2(0.f, 0.f);
          ((float*)&sEa[g][k2 * 2 + 0])[ne] = v.x;
          ((float*)&sEa[g][k2 * 2 + 1])[ne] = v.y;
        }
      }
      int4 sv = *(const int4*)&sIdx[g][1][0];
      if(gl < 18){ float4 eq = sEa[g][gl]; sEamAcc[g][gl] += eq.x + eq.y + eq.z + eq.w; }
      float4 a0 = *(const float4*)(xl + (long)sv.x * F + glc * 4);
      float4 a1 = *(const float4*)(xl + (long)sv.y * F + glc * 4);
      float4 a2 = *(const float4*)(xl + (long)sv.z * F + glc * 4);
      float4 a3 = *(const float4*)(xl + (long)sv.w * F + glc * 4);
      float4 t0 = make_float4(a0.x + xrv.x, a0.y + xrv.y, a0.z + xrv.z, a0.w + xrv.w);
      float4 t1 = make_float4(a1.x + xrv.x, a1.y + xrv.y, a1.z + xrv.z, a1.w + xrv.w);
      float4 t2 = make_float4(a2.x + xrv.x, a2.y + xrv.y, a2.z + xrv.z, a2.w + xrv.w);
      float4 t3 = make_float4(a3.x + xrv.x, a3.y + xrv.y, a3.z + xrv.z, a3.w + xrv.w);
      #pragma unroll
      for(int k = 0; k < 18; ++k){
        float4 w  = sWeT[k * FQ + glc];
        float4 eq = sEa[g][k];
        t0.x = fmaf(w.x, eq.x, t0.x); t0.y = fmaf(w.y, eq.x, t0.y);
        t0.z = fmaf(w.z, eq.x, t0.z); t0.w = fmaf(w.w, eq.x, t0.w);
        t1.x = fmaf(w.x, eq.y, t1.x); t1.y = fmaf(w.y, eq.y, t1.y);
        t1.z = fmaf(w.z, eq.y, t1.z); t1.w = fmaf(w.w, eq.y, t1.w);
        t2.x = fmaf(w.x, eq.z, t2.x); t2.y = fmaf(w.y, eq.z, t2.y);
        t2.z = fmaf(w.z, eq.z, t2.z); t2.w = fmaf(w.w, eq.z, t2.w);
        t3.x = fmaf(w.x, eq.w, t3.x); t3.y = fmaf(w.y, eq.w, t3.y);
        t3.z = fmaf(w.z, eq.w, t3.z); t3.w = fmaf(w.w, eq.w, t3.w);
      }
      float l0 = 0, l1 = 0, l2 = 0, l3 = 0;
      if(act){
        l0 = av.x * lkrelu(t0.x) + av.y * lkrelu(t0.y) + av.z * lkrelu(t0.z) + av.w * lkrelu(t0.w);
        l1 = av.x * lkrelu(t1.x) + av.y * lkrelu(t1.y) + av.z * lkrelu(t1.z) + av.w * lkrelu(t1.w);
        l2 = av.x * lkrelu(t2.x) + av.y * lkrelu(t2.y) + av.z * lkrelu(t2.z) + av.w * lkrelu(t2.w);
        l3 = av.x * lkrelu(t3.x) + av.y * lkrelu(t3.y) + av.z * lkrelu(t3.z) + av.w * lkrelu(t3.w);
      }
      #pragma unroll
      for(int o = G / 2; o; o >>= 1){
        l0 += __shfl_xor(l0, o);
        l1 += __shfl_xor(l1, o);
        l2 += __shfl_xor(l2, o);
        l3 += __shfl_xor(l3, o);
      }
      bool v1 = (p + 1 < r1), v2 = (p + 2 < r1), v3 = (p + 3 < r1);
      if(!v1) l1 = -3.4e38f;
      if(!v2) l2 = -3.4e38f;
      if(!v3) l3 = -3.4e38f;
      float bmax = fmaxf(fmaxf(l0, l1), fmaxf(l2, l3));
      float newm = fmaxf(m, bmax);
      float sc = __expf(m - newm);
      denom *= sc;
      acc.x *= sc; acc.y *= sc; acc.z *= sc; acc.w *= sc;
      m = newm;
      float w0 = __expf(l0 - m);
      float w1 = v1 ? __expf(l1 - m) : 0.0f;
      float w2 = v2 ? __expf(l2 - m) : 0.0f;
      float w3 = v3 ? __expf(l3 - m) : 0.0f;
      denom += w0 + w1 + w2 + w3;
      acc.x += w0 * a0.x + w1 * a1.x + w2 * a2.x + w3 * a3.x;
      acc.y += w0 * a0.y + w1 * a1.y + w2 * a2.y + w3 * a3.y;
      acc.z += w0 * a0.z + w1 * a1.z + w2 * a2.z + w3 * a3.z;
      acc.w += w0 * a0.w + w1 * a1.w + w2 * a2.w + w3 * a3.w;
    }

    // ---- self loop (ea = ea_mean from sEamAcc) ----
    float inv_deg = 1.0f / fmaxf((float)deg, 1.0f);
    float4 ts = make_float4(xlv.x + xrv.x, xlv.y + xrv.y, xlv.z + xrv.z, xlv.w + xrv.w);
    #pragma unroll
    for(int k = 0; k < 18; ++k){
      float em = sEamAcc[g][k] * inv_deg;
      float4 w = sWeT[k * FQ + glc];
      ts.x = fmaf(w.x, em, ts.x); ts.y = fmaf(w.y, em, ts.y);
      ts.z = fmaf(w.z, em, ts.z); ts.w = fmaf(w.w, em, ts.w);
    }
    float sl = 0.0f;
    if(act) sl = av.x * lkrelu(ts.x) + av.y * lkrelu(ts.y) + av.z * lkrelu(ts.z) + av.w * lkrelu(ts.w);
    #pragma unroll
    for(int o = G / 2; o; o >>= 1) sl += __shfl_xor(sl, o);
    float newm = fmaxf(m, sl);
    float sc = __expf(m - newm);
    float ws = __expf(sl - newm);
    denom = denom * sc + ws;
    acc.x = acc.x * sc + ws * xlv.x;
    acc.y = acc.y * sc + ws * xlv.y;
    acc.z = acc.z * sc + ws * xlv.z;
    acc.w = acc.w * sc + ws * xlv.w;

    if(act){
      float inv = 1.0f / denom;
      float4 bv = *(const float4*)(bias + glc * 4);
      float4 ov = make_float4(acc.x * inv + bv.x, acc.y * inv + bv.y,
                              acc.z * inv + bv.z, acc.w * inv + bv.w);
      if(dorelu){
        ov.x = fmaxf(ov.x, 0.f); ov.y = fmaxf(ov.y, 0.f);
        ov.z = fmaxf(ov.z, 0.f); ov.w = fmaxf(ov.w, 0.f);
      }
      *(float4*)(out + (long)node * F + glc * 4) = ov;
    }
  }
}

// fp16-table version (data path, F=100, G=32, no relu, fp32 out); ea in fp16
__global__ __launch_bounds__(256) void k_gat_fused_h(
    const __half* __restrict__ xl, const __half* __restrict__ xr,
    const __half* __restrict__ eah,
    const int* __restrict__ rowoff, const int2* __restrict__ epack,
    const float* __restrict__ We, const float* __restrict__ att,
    const float* __restrict__ bias, float* __restrict__ out, int n)
{
  constexpr int G = 32, NG = 8, F = 100, FQ = 25;
  __shared__ float4 sWeT[18 * FQ];
  __shared__ float4 sAtt[FQ];
  __shared__ float4 sEa[NG][18];
  __shared__ float  sEamAcc[NG][18];
  __shared__ int    sIdx[NG][2][4];

  const int tid = threadIdx.x;
  for(int idx = tid; idx < F * 18; idx += 256){
    int f = idx / 18, k = idx % 18;
    ((float*)sWeT)[k * F + f] = We[idx];
  }
  for(int f = tid; f < F; f += 256) ((float*)sAtt)[f] = att[f];
  __syncthreads();

  const int g = tid / G, gl = tid % G;
  const bool act = (gl * 4 < F);
  const int glc = act ? gl : 0;
  const float4 av = sAtt[glc];

  auto ld4h = [&](const __half* bp, long row) -> float4 {
    uint2 u = *(const uint2*)(bp + row * F + glc * 4);
    float2 lo = __half22float2(*(__half2*)&u.x);
    float2 hi = __half22float2(*(__half2*)&u.y);
    return make_float4(lo.x, lo.y, hi.x, hi.y);
  };

  for(int node = blockIdx.x * NG + g; node < n; node += gridDim.x * NG){
    const int r0 = rowoff[node], r1 = rowoff[node + 1];
    const int deg = r1 - r0;
    if(gl < 18) sEamAcc[g][gl] = 0.0f;
    float4 xlv = ld4h(xl, node);
    float4 xrv = ld4h(xr, node);
    float m = -3.4e38f, denom = 0.0f;
    float4 acc = make_float4(0.f, 0.f, 0.f, 0.f);

    for(int p = r0; p < r1; p += 4){
      if(gl < 4){
        int pp = p + gl; int e = -1, s = 0;
        if(pp < r1){ int2 es = epack[pp]; e = es.x; s = es.y; }
        sIdx[g][0][gl] = e; sIdx[g][1][gl] = s;
      }
      #pragma unroll
      for(int t = 0; t < 2; ++t){
        int u = t * G + gl;
        if(u < 36){
          int ne = u & 3, k2 = u >> 2;
          int e = sIdx[g][0][ne];
          float2 v = make_float2(0.f, 0.f);
          if(e >= 0){
            __half2 h = *(const __half2*)(eah + (long)e * 18 + k2 * 2);
            v = __half22float2(h);
          }
          ((float*)&sEa[g][k2 * 2 + 0])[ne] = v.x;
          ((float*)&sEa[g][k2 * 2 + 1])[ne] = v.y;
        }
      }
      int4 sv = *(const int4*)&sIdx[g][1][0];
      if(gl < 18){ float4 eq = sEa[g][gl]; sEamAcc[g][gl] += eq.x + eq.y + eq.z + eq.w; }
      float4 a0 = ld4h(xl, sv.x);
      float4 a1 = ld4h(xl, sv.y);
      float4 a2 = ld4h(xl, sv.z);
      float4 a3 = ld4h(xl, sv.w);
      float4 t0 = make_float4(a0.x + xrv.x, a0.y + xrv.y, a0.z + xrv.z, a0.w + xrv.w);
      float4 t1 = make_float4(a1.x + xrv.x, a1.y + xrv.y, a1.z + xrv.z, a1.w + xrv.w);
      float4 t2 = make_float4(a2.x + xrv.x, a2.y + xrv.y, a2.z + xrv.z, a2.w + xrv.w);
      float4 t3 = make_float4(a3.x + xrv.x, a3.y + xrv.y, a3.z + xrv.z, a3.w + xrv.w);
      #pragma unroll
      for(int k = 0; k < 18; ++k){
        float4 w  = sWeT[k * FQ + glc];
        float4 eq = sEa[g][k];
        t0.x = fmaf(w.x, eq.x, t0.x); t0.y = fmaf(w.y, eq.x, t0.y);
        t0.z = fmaf(w.z, eq.x, t0.z); t0.w = fmaf(w.w, eq.x, t0.w);
        t1.x = fmaf(w.x, eq.y, t1.x); t1.y = fmaf(w.y, eq.y, t1.y);
        t1.z = fmaf(w.z, eq.y, t1.z); t1.w = fmaf(w.w, eq.y, t1.w);
        t2.x = fmaf(w.x, eq.z, t2.x); t2.y = fmaf(w.y, eq.z, t2.y);
        t2.z = fmaf(w.z, eq.z, t2.z); t2.w = fmaf(w.w, eq.z, t2.w);
        t3.x = fmaf(w.x, eq.w, t3.x); t3.y = fmaf(w.y, eq.w, t3.y);
        t3.z = fmaf(w.z, eq.w, t3.z); t3.w = fmaf(w.w, eq.w, t3.w);
      }
      float l0 = 0, l1 = 0, l2 = 0, l3 = 0;
      if(act){
        l0 = av.x * lkrelu(t0.x) + av.y * lkrelu(t0.y) + av.z * lkrelu(t0.z) + av.w * lkrelu(t0.w);
        l1 = av.x * lkrelu(t1.x) + av.y * lkrelu(t1.y) + av.z * lkrelu(t1.z) + av.w * lkrelu(t1.w);
        l2 = av.x * lkrelu(t2.x) + av.y * lkrelu(t2.y) + av.z * lkrelu(t2.z) + av.w * lkrelu(t2.w);
        l3 = av.x * lkrelu(t3.x) + av.y * lkrelu(t3.y) + av.z * lkrelu(t3.z) + av.w * lkrelu(t3.w);
      }
      #pragma unroll
      for(int o = G / 2; o; o >>= 1){
        l0 += __shfl_xor(l0, o);
        l1 += __shfl_xor(l1, o);
        l2 += __shfl_xor(l2, o);
        l3 += __shfl_xor(l3, o);
      }
      bool v1 = (p + 1 < r1), v2 = (p + 2 < r1), v3 = (p + 3 < r1);
      if(!v1) l1 = -3.4e38f;
      if(!v2) l2 = -3.4e38f;
      if(!v3) l3 = -3.4e38f;
      float bmax = fmaxf(fmaxf(l0, l1), fmaxf(l2, l3));
      float newm = fmaxf(m, bmax);
      float sc = __expf(m - newm);
      denom *= sc;
      acc.x *= sc; acc.y *= sc; acc.z *= sc; acc.w *= sc;
      m = newm;
      float w0 = __expf(l0 - m);
      float w1 = v1 ? __expf(l1 - m) : 0.0f;
      float w2 = v2 ? __expf(l2 - m) : 0.0f;
      float w3 = v3 ? __expf(l3 - m) : 0.0f;
      denom += w0 + w1 + w2 + w3;
      acc.x += w0 * a0.x + w1 * a1.x + w2 * a2.x + w3 * a3.x;
      acc.y += w0 * a0.y + w1 * a1.y + w2 * a2.y + w3 * a3.y;
      acc.z += w0 * a0.z + w1 * a1.z + w2 * a2.z + w3 * a3.z;
      acc.w += w0 * a0.w + w1 * a1.w + w2 * a2.w + w3 * a3.w;
    }

    float inv_deg = 1.0f / fmaxf((float)deg, 1.0f);
    float4 ts = make_float4(xlv.x + xrv.x, xlv.y + xrv.y, xlv.z + xrv.z, xlv.w + xrv.w);
    #pragma unroll
    for(int k = 0; k < 18; ++k){
      float em = sEamAcc[g][k] * inv_deg;
      float4 w = sWeT[k * FQ + glc];
      ts.x = fmaf(w.x, em, ts.x); ts.y = fmaf(w.y, em, ts.y);
      ts.z = fmaf(w.z, em, ts.z); ts.w = fmaf(w.w, em, ts.w);
    }
    float sl = 0.0f;
    if(act) sl = av.x * lkrelu(ts.x) + av.y * lkrelu(ts.y) + av.z * lkrelu(ts.z) + av.w * lkrelu(ts.w);
    #pragma unroll
    for(int o = G / 2; o; o >>= 1) sl += __shfl_xor(sl, o);
    float newm = fmaxf(m, sl);
    float sc = __expf(m - newm);
    float ws = __expf(sl - newm);
    denom = denom * sc + ws;
    acc.x = acc.x * sc + ws * xlv.x;
    acc.y = acc.y * sc + ws * xlv.y;
    acc.z = acc.z * sc + ws * xlv.z;
    acc.w = acc.w * sc + ws * xlv.w;

    if(act){
      float inv = 1.0f / denom;
      float4 bv = *(const float4*)(bias + glc * 4);
      float4 ov = make_float4(acc.x * inv + bv.x, acc.y * inv + bv.y,
                              acc.z * inv + bv.z, acc.w * inv + bv.w);
      *(float4*)(out + (long)node * F + glc * 4) = ov;
    }
  }
}

// ===================== rule pooling (rule_batch sorted) =====================
__global__ void k_rule_starts(const int* __restrict__ rb, int* starts, int NR, int R){
  int r = blockIdx.x * blockDim.x + threadIdx.x;
  if(r > R) return;
  if(r == R){ starts[R] = NR; return; }
  int lo = 0, hi = NR;
  while(lo < hi){ int mid = (lo + hi) >> 1; if(rb[mid] < r) lo = mid + 1; else hi = mid; }
  starts[r] = lo;
}

__global__ void k_pool_rules(const float* __restrict__ h, const int* __restrict__ starts,
                             float* __restrict__ y, int R, int F){
  long idx = (long)blockIdx.x * blockDim.x + threadIdx.x;
  long total = (long)R * F;
  if(idx >= total) return;
  int r = (int)(idx / F);
  int f = (int)(idx % F);
  int s0 = starts[r], s1 = starts[r + 1];
  float a = 0.0f;
  for(int i = s0; i < s1; i++) a += h[(long)i * F + f];
  y[idx] = a / fmaxf((float)(s1 - s0), 1.0f);
}

// ===================== global mean (register accumulate) =====================
__global__ __launch_bounds__(256) void k_pool_all(
    const float* __restrict__ g, float* xp, int n, int F)
{
  const int lane = threadIdx.x & 63;
  const int wid  = threadIdx.x >> 6;
  const int nw   = 4;
  float a0 = 0.0f, a1 = 0.0f;
  const bool ok0 = lane < F, ok1 = lane + 64 < F;
  for(int r = blockIdx.x * nw + wid; r < n; r += gridDim.x * nw){
    const float* row = g + (long)r * F;
    if(ok0) a0 += row[lane];
    if(ok1) a1 += row[lane + 64];
  }
  __shared__ float s[4][128];
  s[wid][lane] = a0;
  s[wid][lane + 64] = a1;
  __syncthreads();
  if(wid == 0){
    float t0 = s[0][lane] + s[1][lane] + s[2][lane] + s[3][lane];
    float t1 = s[0][lane + 64] + s[1][lane + 64] + s[2][lane + 64] + s[3][lane + 64];
    if(ok0 && t0 != 0.0f) atomicAdd(&xp[lane], t0);
    if(ok1 && t1 != 0.0f) atomicAdd(&xp[lane + 64], t1);
  }
}

// ===================== fused bilinear head =====================
__global__ __launch_bounds__(512) void k_bil(
    const float* __restrict__ xp, const float* __restrict__ Wb,
    const float* __restrict__ y, const float* __restrict__ bilb,
    float* __restrict__ out, float inv_n, int R)
{
  __shared__ float v[100];
  int t = threadIdx.x;
  if(t < 100){
    float a = 0.0f;
    for(int d = 0; d < 100; d++) a += xp[d] * Wb[d * 100 + t];
    v[t] = a * inv_n;
  }
  __syncthreads();
  for(int r = t; r < R; r += 512){
    float a = 0.0f;
    const float* yr = y + (long)r * 100;
    for(int e = 0; e < 100; e++) a += v[e] * yr[e];
    out[r] = a + bilb[0];
  }
}

// ------------------------------------------------------------------
static inline int nblk(long n){
  long b = (n + 255) / 256;
  if(b > 20480) b = 20480;
  if(b < 1) b = 1;
  return (int)b;
}

struct GatParams { const float *Wl,*bl,*Wr,*br,*We,*att,*b; };

static void scan_launch(const int* degi, int* bsum, int* rowoff, int* pos,
                        int n, hipStream_t stream){
  int B = (n + 1023) / 1024;
  k_scan_sum  <<<B, 1024, 0, stream>>>(degi, bsum, n);
  k_scan_bsum <<<1, 128,  0, stream>>>(bsum, rowoff, B, n);
  k_scan_apply<<<B, 1024, 0, stream>>>(degi, bsum, rowoff, pos, n);
}

template<int G, int F>
static void gat_fused_launch(const float* xl, const float* xr, const float* ea,
                             const int* rowoff, const int2* epack,
                             const float* We, const float* att, const float* bias,
                             float* out, int n, int dorelu, hipStream_t stream){
  constexpr int NG = 256 / G;
  long nb = ((long)n + NG - 1) / NG;
  int grid = (int)(nb < 4096 ? nb : 4096);
  k_gat_fused<G, F><<<grid, 256, 0, stream>>>(xl, xr, ea, rowoff, epack,
                                              We, att, bias, out, n, dorelu);
}

// fp32 GATv2 layer (rule path): 2 GEMMs + fused kernel
static void run_gatv2(const float* x, int fin, int fout, int n,
                      const float* ea,
                      GatParams P, float* out, int dorelu,
                      float* xl, float* xr,
                      const int* rowoff, const int2* epack, hipStream_t stream){
  gemm_launch(x, P.Wl, P.bl, xl, n, fin, fout, 0, stream);
  gemm_launch(x, P.Wr, P.br, xr, n, fin, fout, 0, stream);
  if(fout == 100)
    gat_fused_launch<32, 100>(xl, xr, ea, rowoff, epack, P.We, P.att, P.b,
                              out, n, dorelu, stream);
  else
    gat_fused_launch<64, 200>(xl, xr, ea, rowoff, epack, P.We, P.att, P.b,
                              out, n, dorelu, stream);
}

extern "C" void kernel_launch(void* const* d_in, const int* in_sizes, int n_in,
                              void* d_out, int out_size, void* d_ws, size_t ws_size,
                              hipStream_t stream){
  const float* x   = (const float*)d_in[0];
  const float* ea  = (const float*)d_in[1];
  const float* rx  = (const float*)d_in[2];
  const float* rea = (const float*)d_in[3];
  GatParams g0{ (const float*)d_in[4],  (const float*)d_in[5],  (const float*)d_in[6],
                (const float*)d_in[7],  (const float*)d_in[8],  (const float*)d_in[9],
                (const float*)d_in[10] };
  GatParams g1{ (const float*)d_in[11], (const float*)d_in[12], (const float*)d_in[13],
                (const float*)d_in[14], (const float*)d_in[15], (const float*)d_in[16],
                (const float*)d_in[17] };
  GatParams g2{ (const float*)d_in[18], (const float*)d_in[19], (const float*)d_in[20],
                (const float*)d_in[21], (const float*)d_in[22], (const float*)d_in[23],
                (const float*)d_in[24] };
  const float* lin_W = (const float*)d_in[25]; const float* lin_b = (const float*)d_in[26];
  const float* f1_W  = (const float*)d_in[27]; const float* f1_b  = (const float*)d_in[28];
  const float* f2_W  = (const float*)d_in[29]; const float* f2_b  = (const float*)d_in[30];
  const float* f3_W  = (const float*)d_in[31]; const float* f3_b  = (const float*)d_in[32];
  const float* bilW  = (const float*)d_in[33]; const float* bilb  = (const float*)d_in[34];
  const int* ei  = (const int*)d_in[35];
  const int* rei = (const int*)d_in[37];
  const int* rb  = (const int*)d_in[38];

  const int N  = in_sizes[0] / 16;
  const int E  = in_sizes[1] / 18;
  const int NR = in_sizes[2] / 16;
  const int ER = in_sizes[3] / 18;
  const int R  = out_size;

  float* Wf = (float*)d_ws;
  size_t off = 0;
  auto alloc  = [&](size_t nf){ nf = (nf + 1) & ~(size_t)1; float* p = Wf + off; off += nf; return p; };
  auto alloci = [&](size_t ni){ ni = (ni + 1) & ~(size_t)1; int* p = (int*)(Wf + off); off += ni; return p; };

  // persistent head
  float* y0 = alloc((size_t)R * 400);
  float* y1 = alloc((size_t)R * 200);
  float* y2 = alloc((size_t)R * 100);
  float* y3 = alloc((size_t)R * 100);
  float* xp = alloc(128);
  int* starts = alloci(R + 1);
  const size_t arena = off;

  // ================= rule path (fp32) =================
  {
    off = arena;
    float* h1 = alloc((size_t)NR * 100);
    float* h2 = alloc((size_t)NR * 200);
    float* xl = alloc((size_t)NR * 200);
    float* xr = alloc((size_t)NR * 200);
    int* rowoff = alloci(NR + 1);
    int* degi   = alloci(NR);
    int* pos    = alloci(NR);
    int* bsum   = alloci(128);
    int2* epack = (int2*)alloci((size_t)ER * 2);
    const int* rsrc = rei; const int* rdst = rei + ER;

    hipMemsetAsync(degi, 0, (size_t)NR * 4, stream);
    k_deg<<<nblk(ER), 256, 0, stream>>>(rdst, degi, ER);
    scan_launch(degi, bsum, rowoff, pos, NR, stream);
    k_fill<<<nblk(ER), 256, 0, stream>>>(rdst, rsrc, pos, epack, ER);

    run_gatv2(rx, 16, 100, NR, rea, g1, h1, 1, xl, xr, rowoff, epack, stream);
    run_gatv2(h1, 100, 200, NR, rea, g2, h2, 1, xl, xr, rowoff, epack, stream);

    float* hlin = xl;  // NR*400 floats (xl+xr contiguous)
    gemm_launch(h2, lin_W, lin_b, hlin, NR, 200, 400, 0, stream);

    k_rule_starts<<<(R + 256) / 256, 256, 0, stream>>>(rb, starts, NR, R);
    k_pool_rules<<<nblk((long)R * 400), 256, 0, stream>>>(hlin, starts, y0, R, 400);

    gemm_launch(y0, f1_W, f1_b, y1, R, 400, 200, 1, stream);
    gemm_launch(y1, f2_W, f2_b, y2, R, 200, 100, 1, stream);
    gemm_launch(y2, f3_W, f3_b, y3, R, 100, 100, 0, stream);
  }

  // ================= data path (fp16 gather tables, fused GAT) =================
  {
    off = arena;
    float* g  = alloc((size_t)N * 100);
    __half* xlh = (__half*)alloc((size_t)N * 50);   // N*100 halfs
    __half* xrh = (__half*)alloc((size_t)N * 50);
    __half* eah = (__half*)alloc((size_t)E * 9);    // E*18 halfs
    int* rowoff = alloci((size_t)N + 1);
    int* degi   = alloci(N);
    int* pos    = alloci(N);
    int* bsum   = alloci(128);
    int2* epack = (int2*)alloci((size_t)E * 2);
    const int* srcp = ei; const int* dstp = ei + E;

    hipMemsetAsync(degi, 0, (size_t)N * 4, stream);
    k_deg<<<nblk(E), 256, 0, stream>>>(dstp, degi, E);
    scan_launch(degi, bsum, rowoff, pos, N, stream);
    k_fill<<<nblk(E), 256, 0, stream>>>(dstp, srcp, pos, epack, E);
    k_cvt_ea_h<<<nblk((long)E * 9), 256, 0, stream>>>(ea, eah, (long)E * 9);

    gemm_h_launch(x, g0.Wl, g0.bl, xlh, N, 16, 100, stream);
    gemm_h_launch(x, g0.Wr, g0.br, xrh, N, 16, 100, stream);
    {
      long nb = ((long)N + 7) / 8;
      int grid = (int)(nb < 4096 ? nb : 4096);
      k_gat_fused_h<<<grid, 256, 0, stream>>>(xlh, xrh, eah, rowoff, epack,
                                              g0.We, g0.att, g0.b, g, N);
    }

    hipMemsetAsync(xp, 0, 128 * 4, stream);
    k_pool_all<<<1024, 256, 0, stream>>>(g, xp, N, 100);
    k_bil<<<1, 512, 0, stream>>>(xp, bilW, y3, bilb, (float*)d_out, 1.0f / (float)N, R);
  }
}

// Round 20
// 852.573 us; speedup vs baseline: 1.0216x; 1.0216x over previous
//
#include <hip/hip_runtime.h>
#include <hip/hip_fp16.h>

#define NS 0.2f  // leaky_relu negative slope

// NOTE (R11-R19 lessons): k_gat_fused_h throughput is a pure function of
// occupancy (64 VGPR -> 38% occ -> 245us; 76->29%->323; 112->19%->375;
// 144->10%->660). Register-costing ILP levers (reg-hoist, NE=8, index
// prefetch, s_setprio) ALL regressed. fp16-ea (R19) improved the fused kernel
// 245->228 but its conversion pass cost more than it saved -> reverted.
// Wins were zero-cost structural only: R18 int2 epack (eidx+src packed,
// removes one dependent global-load hop; FETCH 382->311MB, 264->245us).
// This is the R18 optimum (total 859us).

// ===================== CSR construction =====================
__global__ void k_deg(const int* __restrict__ dst, int* degi, int E){
  int stride = gridDim.x * blockDim.x;
  for(int e = blockIdx.x * blockDim.x + threadIdx.x; e < E; e += stride)
    atomicAdd(&degi[dst[e]], 1);
}

__device__ __forceinline__ int wave_iscan(int v, int lane){
  #pragma unroll
  for(int o = 1; o < 64; o <<= 1){
    int t = __shfl_up(v, o);
    if(lane >= o) v += t;
  }
  return v;
}

// ---- 3-phase multi-block exclusive scan ----
__global__ __launch_bounds__(1024) void k_scan_sum(
    const int* __restrict__ deg, int* __restrict__ bsum, int n)
{
  __shared__ int wsum[16];
  const int lane = threadIdx.x & 63;
  const int w = threadIdx.x >> 6;
  int idx = blockIdx.x * 1024 + threadIdx.x;
  int v = (idx < n) ? deg[idx] : 0;
  #pragma unroll
  for(int o = 32; o; o >>= 1) v += __shfl_xor(v, o);
  if(lane == 0) wsum[w] = v;
  __syncthreads();
  if(w == 0){
    int s = (lane < 16) ? wsum[lane] : 0;
    #pragma unroll
    for(int o = 8; o; o >>= 1) s += __shfl_xor(s, o);
    if(lane == 0) bsum[blockIdx.x] = s;
  }
}

__global__ __launch_bounds__(128) void k_scan_bsum(
    int* __restrict__ bsum, int* __restrict__ rowoff, int B, int n)
{
  __shared__ int wtot[2];
  const int lane = threadIdx.x & 63;
  const int w = threadIdx.x >> 6;
  int t = threadIdx.x;
  int v = (t < B) ? bsum[t] : 0;
  int inc = wave_iscan(v, lane);
  if(lane == 63) wtot[w] = inc;
  __syncthreads();
  int off = (w > 0) ? wtot[0] : 0;
  if(t < B) bsum[t] = off + inc - v;   // exclusive
  if(t == 0) rowoff[n] = wtot[0] + wtot[1];
}

__global__ __launch_bounds__(1024) void k_scan_apply(
    const int* __restrict__ deg, const int* __restrict__ bsum,
    int* __restrict__ rowoff, int* __restrict__ pos, int n)
{
  __shared__ int wsum[16];
  const int lane = threadIdx.x & 63;
  const int w = threadIdx.x >> 6;
  int idx = blockIdx.x * 1024 + threadIdx.x;
  int v = (idx < n) ? deg[idx] : 0;
  int inc = wave_iscan(v, lane);
  if(lane == 63) wsum[w] = inc;
  __syncthreads();
  if(w == 0){
    int s = (lane < 16) ? wsum[lane] : 0;
    s = wave_iscan(s, lane);
    if(lane < 16) wsum[lane] = s;
  }
  __syncthreads();
  int woff = (w > 0) ? wsum[w - 1] : 0;
  if(idx < n){
    int ex = bsum[blockIdx.x] + woff + inc - v;
    rowoff[idx] = ex;
    pos[idx] = ex;
  }
}

// writes packed {e, src[e]} at CSR slot (R18: removes eidx->src dependent hop)
__global__ void k_fill(const int* __restrict__ dst, const int* __restrict__ src,
                       int* pos, int2* epack, int E){
  int stride = gridDim.x * blockDim.x;
  for(int e = blockIdx.x * blockDim.x + threadIdx.x; e < E; e += stride){
    int slot = atomicAdd(&pos[dst[e]], 1);
    epack[slot] = make_int2(e, src[e]);
  }
}

// ===================== tiled GEMM: C = A @ W^T + b (k-major LDS, float4 reads) =====================
#define BM 64
#define BN 64
#define BK 16
__global__ __launch_bounds__(256) void k_gemm(
    const float* __restrict__ A, const float* __restrict__ W,
    const float* __restrict__ b, float* __restrict__ C,
    int n, int K, int M, int dorelu)
{
  __shared__ float As[BK][BM + 4];
  __shared__ float Bs[BK][BN + 4];
  const int bi = blockIdx.x * BM;
  const int bj = blockIdx.y * BN;
  const int tid = threadIdx.x;
  const int tr = tid / 16, tc = tid % 16;
  float acc[4][4] = {};
  for(int k0 = 0; k0 < K; k0 += BK){
    for(int l = tid; l < BM * BK; l += 256){
      int c = l % BK, r = l / BK;
      int gr = bi + r, gc = k0 + c;
      As[c][r] = (gr < n && gc < K) ? A[(long)gr * K + gc] : 0.0f;
    }
    for(int l = tid; l < BN * BK; l += 256){
      int c = l % BK, r = l / BK;
      int gr = bj + r, gc = k0 + c;
      Bs[c][r] = (gr < M && gc < K) ? W[(long)gr * K + gc] : 0.0f;
    }
    __syncthreads();
    #pragma unroll
    for(int kk = 0; kk < BK; ++kk){
      float4 av = *(const float4*)&As[kk][tr * 4];
      float4 bv = *(const float4*)&Bs[kk][tc * 4];
      acc[0][0] = fmaf(av.x, bv.x, acc[0][0]); acc[0][1] = fmaf(av.x, bv.y, acc[0][1]);
      acc[0][2] = fmaf(av.x, bv.z, acc[0][2]); acc[0][3] = fmaf(av.x, bv.w, acc[0][3]);
      acc[1][0] = fmaf(av.y, bv.x, acc[1][0]); acc[1][1] = fmaf(av.y, bv.y, acc[1][1]);
      acc[1][2] = fmaf(av.y, bv.z, acc[1][2]); acc[1][3] = fmaf(av.y, bv.w, acc[1][3]);
      acc[2][0] = fmaf(av.z, bv.x, acc[2][0]); acc[2][1] = fmaf(av.z, bv.y, acc[2][1]);
      acc[2][2] = fmaf(av.z, bv.z, acc[2][2]); acc[2][3] = fmaf(av.z, bv.w, acc[2][3]);
      acc[3][0] = fmaf(av.w, bv.x, acc[3][0]); acc[3][1] = fmaf(av.w, bv.y, acc[3][1]);
      acc[3][2] = fmaf(av.w, bv.z, acc[3][2]); acc[3][3] = fmaf(av.w, bv.w, acc[3][3]);
    }
    __syncthreads();
  }
  for(int r = 0; r < 4; r++){
    int gr = bi + tr * 4 + r;
    if(gr >= n) continue;
    for(int c = 0; c < 4; c++){
      int gc = bj + tc * 4 + c;
      if(gc >= M) continue;
      float val = acc[r][c] + b[gc];
      C[(long)gr * M + gc] = dorelu ? fmaxf(val, 0.0f) : val;
    }
  }
}

// fp16-output variant (data-path xl/xr tables)
__global__ __launch_bounds__(256) void k_gemm_h(
    const float* __restrict__ A, const float* __restrict__ W,
    const float* __restrict__ b, __half* __restrict__ C,
    int n, int K, int M)
{
  __shared__ float As[BK][BM + 4];
  __shared__ float Bs[BK][BN + 4];
  const int bi = blockIdx.x * BM;
  const int bj = blockIdx.y * BN;
  const int tid = threadIdx.x;
  const int tr = tid / 16, tc = tid % 16;
  float acc[4][4] = {};
  for(int k0 = 0; k0 < K; k0 += BK){
    for(int l = tid; l < BM * BK; l += 256){
      int c = l % BK, r = l / BK;
      int gr = bi + r, gc = k0 + c;
      As[c][r] = (gr < n && gc < K) ? A[(long)gr * K + gc] : 0.0f;
    }
    for(int l = tid; l < BN * BK; l += 256){
      int c = l % BK, r = l / BK;
      int gr = bj + r, gc = k0 + c;
      Bs[c][r] = (gr < M && gc < K) ? W[(long)gr * K + gc] : 0.0f;
    }
    __syncthreads();
    #pragma unroll
    for(int kk = 0; kk < BK; ++kk){
      float4 av = *(const float4*)&As[kk][tr * 4];
      float4 bv = *(const float4*)&Bs[kk][tc * 4];
      acc[0][0] = fmaf(av.x, bv.x, acc[0][0]); acc[0][1] = fmaf(av.x, bv.y, acc[0][1]);
      acc[0][2] = fmaf(av.x, bv.z, acc[0][2]); acc[0][3] = fmaf(av.x, bv.w, acc[0][3]);
      acc[1][0] = fmaf(av.y, bv.x, acc[1][0]); acc[1][1] = fmaf(av.y, bv.y, acc[1][1]);
      acc[1][2] = fmaf(av.y, bv.z, acc[1][2]); acc[1][3] = fmaf(av.y, bv.w, acc[1][3]);
      acc[2][0] = fmaf(av.z, bv.x, acc[2][0]); acc[2][1] = fmaf(av.z, bv.y, acc[2][1]);
      acc[2][2] = fmaf(av.z, bv.z, acc[2][2]); acc[2][3] = fmaf(av.z, bv.w, acc[2][3]);
      acc[3][0] = fmaf(av.w, bv.x, acc[3][0]); acc[3][1] = fmaf(av.w, bv.y, acc[3][1]);
      acc[3][2] = fmaf(av.w, bv.z, acc[3][2]); acc[3][3] = fmaf(av.w, bv.w, acc[3][3]);
    }
    __syncthreads();
  }
  for(int r = 0; r < 4; r++){
    int gr = bi + tr * 4 + r;
    if(gr >= n) continue;
    int gc0 = bj + tc * 4;
    float v[4];
    #pragma unroll
    for(int c = 0; c < 4; c++){
      int gc = gc0 + c;
      v[c] = (gc < M) ? acc[r][c] + b[gc] : 0.0f;
    }
    __half* Crow = C + (long)gr * M;
    if(gc0 + 3 < M){
      *(__half2*)(Crow + gc0)     = __halves2half2(__float2half(v[0]), __float2half(v[1]));
      *(__half2*)(Crow + gc0 + 2) = __halves2half2(__float2half(v[2]), __float2half(v[3]));
    } else {
      for(int c = 0; c < 4; c++){
        int gc = gc0 + c;
        if(gc < M) Crow[gc] = __float2half(v[c]);
      }
    }
  }
}

static void gemm_launch(const float* A, const float* W, const float* b, float* C,
                        int n, int K, int M, int relu, hipStream_t s){
  dim3 grid((n + BM - 1) / BM, (M + BN - 1) / BN);
  k_gemm<<<grid, 256, 0, s>>>(A, W, b, C, n, K, M, relu);
}

static void gemm_h_launch(const float* A, const float* W, const float* b, __half* C,
                          int n, int K, int M, hipStream_t s){
  dim3 grid((n + BM - 1) / BM, (M + BN - 1) / BN);
  k_gemm_h<<<grid, 256, 0, s>>>(A, W, b, C, n, K, M);
}

__device__ __forceinline__ float lkrelu(float t){ return (t > 0.0f) ? t : NS * t; }

// ===================== fused GATv2 (fp32, rule path): NE=4 =====================
template<int G, int F>
__global__ __launch_bounds__(256) void k_gat_fused(
    const float* __restrict__ xl, const float* __restrict__ xr,
    const float* __restrict__ ea,
    const int* __restrict__ rowoff, const int2* __restrict__ epack,
    const float* __restrict__ We, const float* __restrict__ att,
    const float* __restrict__ bias, float* __restrict__ out,
    int n, int dorelu)
{
  constexpr int NG = 256 / G;
  constexpr int FQ = F / 4;
  __shared__ float4 sWeT[18 * FQ];
  __shared__ float4 sAtt[FQ];
  __shared__ float4 sEa[NG][18];
  __shared__ float  sEamAcc[NG][18];
  __shared__ int    sIdx[NG][2][4];

  const int tid = threadIdx.x;
  for(int idx = tid; idx < F * 18; idx += 256){
    int f = idx / 18, k = idx % 18;
    ((float*)sWeT)[k * F + f] = We[idx];
  }
  for(int f = tid; f < F; f += 256) ((float*)sAtt)[f] = att[f];
  __syncthreads();

  const int g = tid / G, gl = tid % G;
  const bool act = (gl * 4 < F);
  const int glc = act ? gl : 0;
  const float4 av = sAtt[glc];

  for(int node = blockIdx.x * NG + g; node < n; node += gridDim.x * NG){
    const int r0 = rowoff[node], r1 = rowoff[node + 1];
    const int deg = r1 - r0;
    if(gl < 18) sEamAcc[g][gl] = 0.0f;
    float4 xlv = *(const float4*)(xl + (long)node * F + glc * 4);
    float4 xrv = *(const float4*)(xr + (long)node * F + glc * 4);
    float m = -3.4e38f, denom = 0.0f;
    float4 acc = make_float4(0.f, 0.f, 0.f, 0.f);

    for(int p = r0; p < r1; p += 4){
      if(gl < 4){
        int pp = p + gl; int e = -1, s = 0;
        if(pp < r1){ int2 es = epack[pp]; e = es.x; s = es.y; }
        sIdx[g][0][gl] = e; sIdx[g][1][gl] = s;
      }
      #pragma unroll
      for(int t = 0; t < (36 + G - 1) / G; ++t){
        int u = t * G + gl;
        if(u < 36){
          int ne = u & 3, k2 = u >> 2;
          int e = sIdx[g][0][ne];
          float2 v = (e >= 0) ? *(const float2*)(ea + (long)e * 18 + k2 * 2)
                              : make_float2(0.f, 0.f);
          ((float*)&sEa[g][k2 * 2 + 0])[ne] = v.x;
          ((float*)&sEa[g][k2 * 2 + 1])[ne] = v.y;
        }
      }
      int4 sv = *(const int4*)&sIdx[g][1][0];
      if(gl < 18){ float4 eq = sEa[g][gl]; sEamAcc[g][gl] += eq.x + eq.y + eq.z + eq.w; }
      float4 a0 = *(const float4*)(xl + (long)sv.x * F + glc * 4);
      float4 a1 = *(const float4*)(xl + (long)sv.y * F + glc * 4);
      float4 a2 = *(const float4*)(xl + (long)sv.z * F + glc * 4);
      float4 a3 = *(const float4*)(xl + (long)sv.w * F + glc * 4);
      float4 t0 = make_float4(a0.x + xrv.x, a0.y + xrv.y, a0.z + xrv.z, a0.w + xrv.w);
      float4 t1 = make_float4(a1.x + xrv.x, a1.y + xrv.y, a1.z + xrv.z, a1.w + xrv.w);
      float4 t2 = make_float4(a2.x + xrv.x, a2.y + xrv.y, a2.z + xrv.z, a2.w + xrv.w);
      float4 t3 = make_float4(a3.x + xrv.x, a3.y + xrv.y, a3.z + xrv.z, a3.w + xrv.w);
      #pragma unroll
      for(int k = 0; k < 18; ++k){
        float4 w  = sWeT[k * FQ + glc];
        float4 eq = sEa[g][k];
        t0.x = fmaf(w.x, eq.x, t0.x); t0.y = fmaf(w.y, eq.x, t0.y);
        t0.z = fmaf(w.z, eq.x, t0.z); t0.w = fmaf(w.w, eq.x, t0.w);
        t1.x = fmaf(w.x, eq.y, t1.x); t1.y = fmaf(w.y, eq.y, t1.y);
        t1.z = fmaf(w.z, eq.y, t1.z); t1.w = fmaf(w.w, eq.y, t1.w);
        t2.x = fmaf(w.x, eq.z, t2.x); t2.y = fmaf(w.y, eq.z, t2.y);
        t2.z = fmaf(w.z, eq.z, t2.z); t2.w = fmaf(w.w, eq.z, t2.w);
        t3.x = fmaf(w.x, eq.w, t3.x); t3.y = fmaf(w.y, eq.w, t3.y);
        t3.z = fmaf(w.z, eq.w, t3.z); t3.w = fmaf(w.w, eq.w, t3.w);
      }
      float l0 = 0, l1 = 0, l2 = 0, l3 = 0;
      if(act){
        l0 = av.x * lkrelu(t0.x) + av.y * lkrelu(t0.y) + av.z * lkrelu(t0.z) + av.w * lkrelu(t0.w);
        l1 = av.x * lkrelu(t1.x) + av.y * lkrelu(t1.y) + av.z * lkrelu(t1.z) + av.w * lkrelu(t1.w);
        l2 = av.x * lkrelu(t2.x) + av.y * lkrelu(t2.y) + av.z * lkrelu(t2.z) + av.w * lkrelu(t2.w);
        l3 = av.x * lkrelu(t3.x) + av.y * lkrelu(t3.y) + av.z * lkrelu(t3.z) + av.w * lkrelu(t3.w);
      }
      #pragma unroll
      for(int o = G / 2; o; o >>= 1){
        l0 += __shfl_xor(l0, o);
        l1 += __shfl_xor(l1, o);
        l2 += __shfl_xor(l2, o);
        l3 += __shfl_xor(l3, o);
      }
      bool v1 = (p + 1 < r1), v2 = (p + 2 < r1), v3 = (p + 3 < r1);
      if(!v1) l1 = -3.4e38f;
      if(!v2) l2 = -3.4e38f;
      if(!v3) l3 = -3.4e38f;
      float bmax = fmaxf(fmaxf(l0, l1), fmaxf(l2, l3));
      float newm = fmaxf(m, bmax);
      float sc = __expf(m - newm);
      denom *= sc;
      acc.x *= sc; acc.y *= sc; acc.z *= sc; acc.w *= sc;
      m = newm;
      float w0 = __expf(l0 - m);
      float w1 = v1 ? __expf(l1 - m) : 0.0f;
      float w2 = v2 ? __expf(l2 - m) : 0.0f;
      float w3 = v3 ? __expf(l3 - m) : 0.0f;
      denom += w0 + w1 + w2 + w3;
      acc.x += w0 * a0.x + w1 * a1.x + w2 * a2.x + w3 * a3.x;
      acc.y += w0 * a0.y + w1 * a1.y + w2 * a2.y + w3 * a3.y;
      acc.z += w0 * a0.z + w1 * a1.z + w2 * a2.z + w3 * a3.z;
      acc.w += w0 * a0.w + w1 * a1.w + w2 * a2.w + w3 * a3.w;
    }

    // ---- self loop (ea = ea_mean from sEamAcc) ----
    float inv_deg = 1.0f / fmaxf((float)deg, 1.0f);
    float4 ts = make_float4(xlv.x + xrv.x, xlv.y + xrv.y, xlv.z + xrv.z, xlv.w + xrv.w);
    #pragma unroll
    for(int k = 0; k < 18; ++k){
      float em = sEamAcc[g][k] * inv_deg;
      float4 w = sWeT[k * FQ + glc];
      ts.x = fmaf(w.x, em, ts.x); ts.y = fmaf(w.y, em, ts.y);
      ts.z = fmaf(w.z, em, ts.z); ts.w = fmaf(w.w, em, ts.w);
    }
    float sl = 0.0f;
    if(act) sl = av.x * lkrelu(ts.x) + av.y * lkrelu(ts.y) + av.z * lkrelu(ts.z) + av.w * lkrelu(ts.w);
    #pragma unroll
    for(int o = G / 2; o; o >>= 1) sl += __shfl_xor(sl, o);
    float newm = fmaxf(m, sl);
    float sc = __expf(m - newm);
    float ws = __expf(sl - newm);
    denom = denom * sc + ws;
    acc.x = acc.x * sc + ws * xlv.x;
    acc.y = acc.y * sc + ws * xlv.y;
    acc.z = acc.z * sc + ws * xlv.z;
    acc.w = acc.w * sc + ws * xlv.w;

    if(act){
      float inv = 1.0f / denom;
      float4 bv = *(const float4*)(bias + glc * 4);
      float4 ov = make_float4(acc.x * inv + bv.x, acc.y * inv + bv.y,
                              acc.z * inv + bv.z, acc.w * inv + bv.w);
      if(dorelu){
        ov.x = fmaxf(ov.x, 0.f); ov.y = fmaxf(ov.y, 0.f);
        ov.z = fmaxf(ov.z, 0.f); ov.w = fmaxf(ov.w, 0.f);
      }
      *(float4*)(out + (long)node * F + glc * 4) = ov;
    }
  }
}

// fp16-table version (data path, F=100, G=32, no relu, fp32 out)
__global__ __launch_bounds__(256) void k_gat_fused_h(
    const __half* __restrict__ xl, const __half* __restrict__ xr,
    const float* __restrict__ ea,
    const int* __restrict__ rowoff, const int2* __restrict__ epack,
    const float* __restrict__ We, const float* __restrict__ att,
    const float* __restrict__ bias, float* __restrict__ out, int n)
{
  constexpr int G = 32, NG = 8, F = 100, FQ = 25;
  __shared__ float4 sWeT[18 * FQ];
  __shared__ float4 sAtt[FQ];
  __shared__ float4 sEa[NG][18];
  __shared__ float  sEamAcc[NG][18];
  __shared__ int    sIdx[NG][2][4];

  const int tid = threadIdx.x;
  for(int idx = tid; idx < F * 18; idx += 256){
    int f = idx / 18, k = idx % 18;
    ((float*)sWeT)[k * F + f] = We[idx];
  }
  for(int f = tid; f < F; f += 256) ((float*)sAtt)[f] = att[f];
  __syncthreads();

  const int g = tid / G, gl = tid % G;
  const bool act = (gl * 4 < F);
  const int glc = act ? gl : 0;
  const float4 av = sAtt[glc];

  auto ld4h = [&](const __half* bp, long row) -> float4 {
    uint2 u = *(const uint2*)(bp + row * F + glc * 4);
    float2 lo = __half22float2(*(__half2*)&u.x);
    float2 hi = __half22float2(*(__half2*)&u.y);
    return make_float4(lo.x, lo.y, hi.x, hi.y);
  };

  for(int node = blockIdx.x * NG + g; node < n; node += gridDim.x * NG){
    const int r0 = rowoff[node], r1 = rowoff[node + 1];
    const int deg = r1 - r0;
    if(gl < 18) sEamAcc[g][gl] = 0.0f;
    float4 xlv = ld4h(xl, node);
    float4 xrv = ld4h(xr, node);
    float m = -3.4e38f, denom = 0.0f;
    float4 acc = make_float4(0.f, 0.f, 0.f, 0.f);

    for(int p = r0; p < r1; p += 4){
      if(gl < 4){
        int pp = p + gl; int e = -1, s = 0;
        if(pp < r1){ int2 es = epack[pp]; e = es.x; s = es.y; }
        sIdx[g][0][gl] = e; sIdx[g][1][gl] = s;
      }
      #pragma unroll
      for(int t = 0; t < 2; ++t){
        int u = t * G + gl;
        if(u < 36){
          int ne = u & 3, k2 = u >> 2;
          int e = sIdx[g][0][ne];
          float2 v = (e >= 0) ? *(const float2*)(ea + (long)e * 18 + k2 * 2)
                              : make_float2(0.f, 0.f);
          ((float*)&sEa[g][k2 * 2 + 0])[ne] = v.x;
          ((float*)&sEa[g][k2 * 2 + 1])[ne] = v.y;
        }
      }
      int4 sv = *(const int4*)&sIdx[g][1][0];
      if(gl < 18){ float4 eq = sEa[g][gl]; sEamAcc[g][gl] += eq.x + eq.y + eq.z + eq.w; }
      float4 a0 = ld4h(xl, sv.x);
      float4 a1 = ld4h(xl, sv.y);
      float4 a2 = ld4h(xl, sv.z);
      float4 a3 = ld4h(xl, sv.w);
      float4 t0 = make_float4(a0.x + xrv.x, a0.y + xrv.y, a0.z + xrv.z, a0.w + xrv.w);
      float4 t1 = make_float4(a1.x + xrv.x, a1.y + xrv.y, a1.z + xrv.z, a1.w + xrv.w);
      float4 t2 = make_float4(a2.x + xrv.x, a2.y + xrv.y, a2.z + xrv.z, a2.w + xrv.w);
      float4 t3 = make_float4(a3.x + xrv.x, a3.y + xrv.y, a3.z + xrv.z, a3.w + xrv.w);
      #pragma unroll
      for(int k = 0; k < 18; ++k){
        float4 w  = sWeT[k * FQ + glc];
        float4 eq = sEa[g][k];
        t0.x = fmaf(w.x, eq.x, t0.x); t0.y = fmaf(w.y, eq.x, t0.y);
        t0.z = fmaf(w.z, eq.x, t0.z); t0.w = fmaf(w.w, eq.x, t0.w);
        t1.x = fmaf(w.x, eq.y, t1.x); t1.y = fmaf(w.y, eq.y, t1.y);
        t1.z = fmaf(w.z, eq.y, t1.z); t1.w = fmaf(w.w, eq.y, t1.w);
        t2.x = fmaf(w.x, eq.z, t2.x); t2.y = fmaf(w.y, eq.z, t2.y);
        t2.z = fmaf(w.z, eq.z, t2.z); t2.w = fmaf(w.w, eq.z, t2.w);
        t3.x = fmaf(w.x, eq.w, t3.x); t3.y = fmaf(w.y, eq.w, t3.y);
        t3.z = fmaf(w.z, eq.w, t3.z); t3.w = fmaf(w.w, eq.w, t3.w);
      }
      float l0 = 0, l1 = 0, l2 = 0, l3 = 0;
      if(act){
        l0 = av.x * lkrelu(t0.x) + av.y * lkrelu(t0.y) + av.z * lkrelu(t0.z) + av.w * lkrelu(t0.w);
        l1 = av.x * lkrelu(t1.x) + av.y * lkrelu(t1.y) + av.z * lkrelu(t1.z) + av.w * lkrelu(t1.w);
        l2 = av.x * lkrelu(t2.x) + av.y * lkrelu(t2.y) + av.z * lkrelu(t2.z) + av.w * lkrelu(t2.w);
        l3 = av.x * lkrelu(t3.x) + av.y * lkrelu(t3.y) + av.z * lkrelu(t3.z) + av.w * lkrelu(t3.w);
      }
      #pragma unroll
      for(int o = G / 2; o; o >>= 1){
        l0 += __shfl_xor(l0, o);
        l1 += __shfl_xor(l1, o);
        l2 += __shfl_xor(l2, o);
        l3 += __shfl_xor(l3, o);
      }
      bool v1 = (p + 1 < r1), v2 = (p + 2 < r1), v3 = (p + 3 < r1);
      if(!v1) l1 = -3.4e38f;
      if(!v2) l2 = -3.4e38f;
      if(!v3) l3 = -3.4e38f;
      float bmax = fmaxf(fmaxf(l0, l1), fmaxf(l2, l3));
      float newm = fmaxf(m, bmax);
      float sc = __expf(m - newm);
      denom *= sc;
      acc.x *= sc; acc.y *= sc; acc.z *= sc; acc.w *= sc;
      m = newm;
      float w0 = __expf(l0 - m);
      float w1 = v1 ? __expf(l1 - m) : 0.0f;
      float w2 = v2 ? __expf(l2 - m) : 0.0f;
      float w3 = v3 ? __expf(l3 - m) : 0.0f;
      denom += w0 + w1 + w2 + w3;
      acc.x += w0 * a0.x + w1 * a1.x + w2 * a2.x + w3 * a3.x;
      acc.y += w0 * a0.y + w1 * a1.y + w2 * a2.y + w3 * a3.y;
      acc.z += w0 * a0.z + w1 * a1.z + w2 * a2.z + w3 * a3.z;
      acc.w += w0 * a0.w + w1 * a1.w + w2 * a2.w + w3 * a3.w;
    }

    float inv_deg = 1.0f / fmaxf((float)deg, 1.0f);
    float4 ts = make_float4(xlv.x + xrv.x, xlv.y + xrv.y, xlv.z + xrv.z, xlv.w + xrv.w);
    #pragma unroll
    for(int k = 0; k < 18; ++k){
      float em = sEamAcc[g][k] * inv_deg;
      float4 w = sWeT[k * FQ + glc];
      ts.x = fmaf(w.x, em, ts.x); ts.y = fmaf(w.y, em, ts.y);
      ts.z = fmaf(w.z, em, ts.z); ts.w = fmaf(w.w, em, ts.w);
    }
    float sl = 0.0f;
    if(act) sl = av.x * lkrelu(ts.x) + av.y * lkrelu(ts.y) + av.z * lkrelu(ts.z) + av.w * lkrelu(ts.w);
    #pragma unroll
    for(int o = G / 2; o; o >>= 1) sl += __shfl_xor(sl, o);
    float newm = fmaxf(m, sl);
    float sc = __expf(m - newm);
    float ws = __expf(sl - newm);
    denom = denom * sc + ws;
    acc.x = acc.x * sc + ws * xlv.x;
    acc.y = acc.y * sc + ws * xlv.y;
    acc.z = acc.z * sc + ws * xlv.z;
    acc.w = acc.w * sc + ws * xlv.w;

    if(act){
      float inv = 1.0f / denom;
      float4 bv = *(const float4*)(bias + glc * 4);
      float4 ov = make_float4(acc.x * inv + bv.x, acc.y * inv + bv.y,
                              acc.z * inv + bv.z, acc.w * inv + bv.w);
      *(float4*)(out + (long)node * F + glc * 4) = ov;
    }
  }
}

// ===================== rule pooling (rule_batch sorted) =====================
__global__ void k_rule_starts(const int* __restrict__ rb, int* starts, int NR, int R){
  int r = blockIdx.x * blockDim.x + threadIdx.x;
  if(r > R) return;
  if(r == R){ starts[R] = NR; return; }
  int lo = 0, hi = NR;
  while(lo < hi){ int mid = (lo + hi) >> 1; if(rb[mid] < r) lo = mid + 1; else hi = mid; }
  starts[r] = lo;
}

__global__ void k_pool_rules(const float* __restrict__ h, const int* __restrict__ starts,
                             float* __restrict__ y, int R, int F){
  long idx = (long)blockIdx.x * blockDim.x + threadIdx.x;
  long total = (long)R * F;
  if(idx >= total) return;
  int r = (int)(idx / F);
  int f = (int)(idx % F);
  int s0 = starts[r], s1 = starts[r + 1];
  float a = 0.0f;
  for(int i = s0; i < s1; i++) a += h[(long)i * F + f];
  y[idx] = a / fmaxf((float)(s1 - s0), 1.0f);
}

// ===================== global mean (register accumulate) =====================
__global__ __launch_bounds__(256) void k_pool_all(
    const float* __restrict__ g, float* xp, int n, int F)
{
  const int lane = threadIdx.x & 63;
  const int wid  = threadIdx.x >> 6;
  const int nw   = 4;
  float a0 = 0.0f, a1 = 0.0f;
  const bool ok0 = lane < F, ok1 = lane + 64 < F;
  for(int r = blockIdx.x * nw + wid; r < n; r += gridDim.x * nw){
    const float* row = g + (long)r * F;
    if(ok0) a0 += row[lane];
    if(ok1) a1 += row[lane + 64];
  }
  __shared__ float s[4][128];
  s[wid][lane] = a0;
  s[wid][lane + 64] = a1;
  __syncthreads();
  if(wid == 0){
    float t0 = s[0][lane] + s[1][lane] + s[2][lane] + s[3][lane];
    float t1 = s[0][lane + 64] + s[1][lane + 64] + s[2][lane + 64] + s[3][lane + 64];
    if(ok0 && t0 != 0.0f) atomicAdd(&xp[lane], t0);
    if(ok1 && t1 != 0.0f) atomicAdd(&xp[lane + 64], t1);
  }
}

// ===================== fused bilinear head =====================
__global__ __launch_bounds__(512) void k_bil(
    const float* __restrict__ xp, const float* __restrict__ Wb,
    const float* __restrict__ y, const float* __restrict__ bilb,
    float* __restrict__ out, float inv_n, int R)
{
  __shared__ float v[100];
  int t = threadIdx.x;
  if(t < 100){
    float a = 0.0f;
    for(int d = 0; d < 100; d++) a += xp[d] * Wb[d * 100 + t];
    v[t] = a * inv_n;
  }
  __syncthreads();
  for(int r = t; r < R; r += 512){
    float a = 0.0f;
    const float* yr = y + (long)r * 100;
    for(int e = 0; e < 100; e++) a += v[e] * yr[e];
    out[r] = a + bilb[0];
  }
}

// ------------------------------------------------------------------
static inline int nblk(long n){
  long b = (n + 255) / 256;
  if(b > 20480) b = 20480;
  if(b < 1) b = 1;
  return (int)b;
}

struct GatParams { const float *Wl,*bl,*Wr,*br,*We,*att,*b; };

static void scan_launch(const int* degi, int* bsum, int* rowoff, int* pos,
                        int n, hipStream_t stream){
  int B = (n + 1023) / 1024;
  k_scan_sum  <<<B, 1024, 0, stream>>>(degi, bsum, n);
  k_scan_bsum <<<1, 128,  0, stream>>>(bsum, rowoff, B, n);
  k_scan_apply<<<B, 1024, 0, stream>>>(degi, bsum, rowoff, pos, n);
}

template<int G, int F>
static void gat_fused_launch(const float* xl, const float* xr, const float* ea,
                             const int* rowoff, const int2* epack,
                             const float* We, const float* att, const float* bias,
                             float* out, int n, int dorelu, hipStream_t stream){
  constexpr int NG = 256 / G;
  long nb = ((long)n + NG - 1) / NG;
  int grid = (int)(nb < 4096 ? nb : 4096);
  k_gat_fused<G, F><<<grid, 256, 0, stream>>>(xl, xr, ea, rowoff, epack,
                                              We, att, bias, out, n, dorelu);
}

// fp32 GATv2 layer (rule path): 2 GEMMs + fused kernel
static void run_gatv2(const float* x, int fin, int fout, int n,
                      const float* ea,
                      GatParams P, float* out, int dorelu,
                      float* xl, float* xr,
                      const int* rowoff, const int2* epack, hipStream_t stream){
  gemm_launch(x, P.Wl, P.bl, xl, n, fin, fout, 0, stream);
  gemm_launch(x, P.Wr, P.br, xr, n, fin, fout, 0, stream);
  if(fout == 100)
    gat_fused_launch<32, 100>(xl, xr, ea, rowoff, epack, P.We, P.att, P.b,
                              out, n, dorelu, stream);
  else
    gat_fused_launch<64, 200>(xl, xr, ea, rowoff, epack, P.We, P.att, P.b,
                              out, n, dorelu, stream);
}

extern "C" void kernel_launch(void* const* d_in, const int* in_sizes, int n_in,
                              void* d_out, int out_size, void* d_ws, size_t ws_size,
                              hipStream_t stream){
  const float* x   = (const float*)d_in[0];
  const float* ea  = (const float*)d_in[1];
  const float* rx  = (const float*)d_in[2];
  const float* rea = (const float*)d_in[3];
  GatParams g0{ (const float*)d_in[4],  (const float*)d_in[5],  (const float*)d_in[6],
                (const float*)d_in[7],  (const float*)d_in[8],  (const float*)d_in[9],
                (const float*)d_in[10] };
  GatParams g1{ (const float*)d_in[11], (const float*)d_in[12], (const float*)d_in[13],
                (const float*)d_in[14], (const float*)d_in[15], (const float*)d_in[16],
                (const float*)d_in[17] };
  GatParams g2{ (const float*)d_in[18], (const float*)d_in[19], (const float*)d_in[20],
                (const float*)d_in[21], (const float*)d_in[22], (const float*)d_in[23],
                (const float*)d_in[24] };
  const float* lin_W = (const float*)d_in[25]; const float* lin_b = (const float*)d_in[26];
  const float* f1_W  = (const float*)d_in[27]; const float* f1_b  = (const float*)d_in[28];
  const float* f2_W  = (const float*)d_in[29]; const float* f2_b  = (const float*)d_in[30];
  const float* f3_W  = (const float*)d_in[31]; const float* f3_b  = (const float*)d_in[32];
  const float* bilW  = (const float*)d_in[33]; const float* bilb  = (const float*)d_in[34];
  const int* ei  = (const int*)d_in[35];
  const int* rei = (const int*)d_in[37];
  const int* rb  = (const int*)d_in[38];

  const int N  = in_sizes[0] / 16;
  const int E  = in_sizes[1] / 18;
  const int NR = in_sizes[2] / 16;
  const int ER = in_sizes[3] / 18;
  const int R  = out_size;

  float* Wf = (float*)d_ws;
  size_t off = 0;
  auto alloc  = [&](size_t nf){ nf = (nf + 1) & ~(size_t)1; float* p = Wf + off; off += nf; return p; };
  auto alloci = [&](size_t ni){ ni = (ni + 1) & ~(size_t)1; int* p = (int*)(Wf + off); off += ni; return p; };

  // persistent head
  float* y0 = alloc((size_t)R * 400);
  float* y1 = alloc((size_t)R * 200);
  float* y2 = alloc((size_t)R * 100);
  float* y3 = alloc((size_t)R * 100);
  float* xp = alloc(128);
  int* starts = alloci(R + 1);
  const size_t arena = off;

  // ================= rule path (fp32) =================
  {
    off = arena;
    float* h1 = alloc((size_t)NR * 100);
    float* h2 = alloc((size_t)NR * 200);
    float* xl = alloc((size_t)NR * 200);
    float* xr = alloc((size_t)NR * 200);
    int* rowoff = alloci(NR + 1);
    int* degi   = alloci(NR);
    int* pos    = alloci(NR);
    int* bsum   = alloci(128);
    int2* epack = (int2*)alloci((size_t)ER * 2);
    const int* rsrc = rei; const int* rdst = rei + ER;

    hipMemsetAsync(degi, 0, (size_t)NR * 4, stream);
    k_deg<<<nblk(ER), 256, 0, stream>>>(rdst, degi, ER);
    scan_launch(degi, bsum, rowoff, pos, NR, stream);
    k_fill<<<nblk(ER), 256, 0, stream>>>(rdst, rsrc, pos, epack, ER);

    run_gatv2(rx, 16, 100, NR, rea, g1, h1, 1, xl, xr, rowoff, epack, stream);
    run_gatv2(h1, 100, 200, NR, rea, g2, h2, 1, xl, xr, rowoff, epack, stream);

    float* hlin = xl;  // NR*400 floats (xl+xr contiguous)
    gemm_launch(h2, lin_W, lin_b, hlin, NR, 200, 400, 0, stream);

    k_rule_starts<<<(R + 256) / 256, 256, 0, stream>>>(rb, starts, NR, R);
    k_pool_rules<<<nblk((long)R * 400), 256, 0, stream>>>(hlin, starts, y0, R, 400);

    gemm_launch(y0, f1_W, f1_b, y1, R, 400, 200, 1, stream);
    gemm_launch(y1, f2_W, f2_b, y2, R, 200, 100, 1, stream);
    gemm_launch(y2, f3_W, f3_b, y3, R, 100, 100, 0, stream);
  }

  // ================= data path (fp16 gather tables, fused GAT) =================
  {
    off = arena;
    float* g  = alloc((size_t)N * 100);
    __half* xlh = (__half*)alloc((size_t)N * 50);   // N*100 halfs
    __half* xrh = (__half*)alloc((size_t)N * 50);
    int* rowoff = alloci((size_t)N + 1);
    int* degi   = alloci(N);
    int* pos    = alloci(N);
    int* bsum   = alloci(128);
    int2* epack = (int2*)alloci((size_t)E * 2);
    const int* srcp = ei; const int* dstp = ei + E;

    hipMemsetAsync(degi, 0, (size_t)N * 4, stream);
    k_deg<<<nblk(E), 256, 0, stream>>>(dstp, degi, E);
    scan_launch(degi, bsum, rowoff, pos, N, stream);
    k_fill<<<nblk(E), 256, 0, stream>>>(dstp, srcp, pos, epack, E);

    gemm_h_launch(x, g0.Wl, g0.bl, xlh, N, 16, 100, stream);
    gemm_h_launch(x, g0.Wr, g0.br, xrh, N, 16, 100, stream);
    {
      long nb = ((long)N + 7) / 8;
      int grid = (int)(nb < 4096 ? nb : 4096);
      k_gat_fused_h<<<grid, 256, 0, stream>>>(xlh, xrh, ea, rowoff, epack,
                                              g0.We, g0.att, g0.b, g, N);
    }

    hipMemsetAsync(xp, 0, 128 * 4, stream);
    k_pool_all<<<1024, 256, 0, stream>>>(g, xp, N, 100);
    k_bil<<<1, 512, 0, stream>>>(xp, bilW, y3, bilb, (float*)d_out, 1.0f / (float)N, R);
  }
}